// Round 13
// baseline (377.566 us; speedup 1.0000x reference)
//
#include <hip/hip_runtime.h>
#include <math.h>

#define D 128
#define LSTRIDE 136   // LDS row stride in halves

typedef _Float16 half8 __attribute__((ext_vector_type(8)));
typedef _Float16 half4v __attribute__((ext_vector_type(4)));
typedef _Float16 half2v __attribute__((ext_vector_type(2)));
typedef float f32x4 __attribute__((ext_vector_type(4)));
typedef float f32x2 __attribute__((ext_vector_type(2)));
typedef unsigned char uchar;

// unpack 8 fp8 (e4m3, bytes of a uint2) and accumulate into 8 floats
__device__ __forceinline__ void acc_fp8x8(float* a, uint2 u) {
    f32x2 p0 = __builtin_amdgcn_cvt_pk_f32_fp8((int)u.x, false);
    f32x2 p1 = __builtin_amdgcn_cvt_pk_f32_fp8((int)u.x, true);
    f32x2 p2 = __builtin_amdgcn_cvt_pk_f32_fp8((int)u.y, false);
    f32x2 p3 = __builtin_amdgcn_cvt_pk_f32_fp8((int)u.y, true);
    a[0] += p0[0]; a[1] += p0[1]; a[2] += p1[0]; a[3] += p1[1];
    a[4] += p2[0]; a[5] += p2[1]; a[6] += p3[0]; a[7] += p3[1];
}

// ============ fat1: edge count + within-bucket rank, plus weight pre-pack ============
// blocks [0, countBlocks): counting pass. blocks [countBlocks, countBlocks+32): prepw.

__global__ void k_fat1(const int* __restrict__ ei, int* __restrict__ counts,
                       int* __restrict__ pidx, int E, int countBlocks,
                       const float* __restrict__ convW, _Float16* __restrict__ Wf) {
    if ((int)blockIdx.x < countBlocks) {
        int e0 = (blockIdx.x * blockDim.x + threadIdx.x) * 4;
        if (e0 + 3 < E) {
            int4 d4 = *(const int4*)(ei + E + e0);
            int4 p;
            p.x = atomicAdd(&counts[d4.x], 1);
            p.y = atomicAdd(&counts[d4.y], 1);
            p.z = atomicAdd(&counts[d4.z], 1);
            p.w = atomicAdd(&counts[d4.w], 1);
            *(int4*)(pidx + e0) = p;
        } else {
            for (int e = e0; e < E; e++) pidx[e] = atomicAdd(&counts[ei[E + e]], 1);
        }
    } else {
        // prepw: slot = (s*8+c)*64 + lane; elem j: k = s*32+(lane>>4)*8+j, n = c*16+(lane&15)
        const int bid = blockIdx.x - countBlocks;           // 0..31
        const int l = bid >> 3;                             // layer
        const int slot = (bid & 7) * 256 + threadIdx.x;
        const float* W = convW + (size_t)l * D * D;
        const int p = slot >> 6, ln = slot & 63;
        const int s = p >> 3, c = p & 7;
        const int kbase = s * 32 + ((ln >> 4) << 3);
        const int n = (c << 4) + (ln & 15);
        half8 hv;
#pragma unroll
        for (int j = 0; j < 8; j++) hv[j] = (_Float16)W[(size_t)(kbase + j) * D + n];
        *(half8*)(Wf + (size_t)l * D * D + (size_t)slot * 8) = hv;
    }
}

// scan counts -> rowptr (exclusive, per 1024-block); emits dinv = rsqrt(count+1)
__global__ __launch_bounds__(256) void k_scan1(const int* __restrict__ counts,
                                               int* __restrict__ rowptr,
                                               int* __restrict__ bsums,
                                               float* __restrict__ dinv, int N) {
    __shared__ int sh[256];
    const int t = threadIdx.x;
    const int base = blockIdx.x * 1024 + t * 4;
    int c[4];
#pragma unroll
    for (int j = 0; j < 4; j++) c[j] = (base + j < N) ? counts[base + j] : 0;
#pragma unroll
    for (int j = 0; j < 4; j++)
        if (base + j < N) dinv[base + j] = rsqrtf((float)(c[j] + 1));
    int tsum = c[0] + c[1] + c[2] + c[3];
    sh[t] = tsum;
    __syncthreads();
    for (int off = 1; off < 256; off <<= 1) {
        int v = (t >= off) ? sh[t - off] : 0;
        __syncthreads();
        sh[t] += v;
        __syncthreads();
    }
    int run = (t == 0) ? 0 : sh[t - 1];
    if (t == 255) bsums[blockIdx.x] = sh[255];
#pragma unroll
    for (int j = 0; j < 4; j++) {
        if (base + j <= N) rowptr[base + j] = run;
        run += c[j];
    }
}

// ============ fat2: scan3 (rowptr += block prefix) + cvt (x -> fp8 g0) ============
// blocks [0, scanBlocks): scan3. rest: cvt, 8 elems/thread.

__global__ __launch_bounds__(256) void k_fat2(int* __restrict__ rowptr,
                                              const int* __restrict__ bsums,
                                              int NB, int N, int scanBlocks,
                                              const float* __restrict__ x,
                                              const float* __restrict__ dinv,
                                              uchar* __restrict__ g8) {
    if ((int)blockIdx.x < scanBlocks) {
        __shared__ int pre[128];
        const int t = threadIdx.x;
        if (t < 128) pre[t] = (t < NB) ? bsums[t] : 0;
        __syncthreads();
        for (int off = 1; off < 128; off <<= 1) {
            int v = (t >= off && t < 128) ? pre[t - off] : 0;
            __syncthreads();
            if (t < 128) pre[t] += v;
            __syncthreads();
        }
        int i = blockIdx.x * blockDim.x + t;
        if (i <= N) {
            int b = i >> 10;
            rowptr[i] += (b == 0) ? 0 : pre[b - 1];
        }
    } else {
        int i = (blockIdx.x - scanBlocks) * blockDim.x + threadIdx.x;
        const int n8 = N * (D / 8);
        if (i >= n8) return;
        float s = dinv[i >> 4];
        const float4 v0 = *(const float4*)(x + (size_t)i * 8);
        const float4 v1 = *(const float4*)(x + (size_t)i * 8 + 4);
        int lo = __builtin_amdgcn_cvt_pk_fp8_f32(v0.x * s, v0.y * s, 0, false);
        lo     = __builtin_amdgcn_cvt_pk_fp8_f32(v0.z * s, v0.w * s, lo, true);
        int hi = __builtin_amdgcn_cvt_pk_fp8_f32(v1.x * s, v1.y * s, 0, false);
        hi     = __builtin_amdgcn_cvt_pk_fp8_f32(v1.z * s, v1.w * s, hi, true);
        *(int2*)(g8 + (size_t)i * 8) = make_int2(lo, hi);
    }
}

// pass B: srcs[rowptr[dst] + pidx] = src — no atomics
__global__ void k_fill(const int* __restrict__ ei, const int* __restrict__ rowptr,
                       const int* __restrict__ pidx, int* __restrict__ srcs, int E) {
    int e0 = (blockIdx.x * blockDim.x + threadIdx.x) * 4;
    if (e0 + 3 < E) {
        int4 s4 = *(const int4*)(ei + e0);
        int4 d4 = *(const int4*)(ei + E + e0);
        int4 p4 = *(const int4*)(pidx + e0);
        int r0 = rowptr[d4.x], r1 = rowptr[d4.y], r2 = rowptr[d4.z], r3 = rowptr[d4.w];
        srcs[r0 + p4.x] = s4.x;
        srcs[r1 + p4.y] = s4.y;
        srcs[r2 + p4.z] = s4.z;
        srcs[r3 + p4.w] = s4.w;
    } else {
        for (int e = e0; e < E; e++)
            srcs[rowptr[ei[E + e]] + pidx[e]] = ei[e];
    }
}

// ============ fused layer: out = scale ⊙ relu( (dinv ⊙ Â g) @ W + b ) ============
// R12 structure, fp8 feature storage: 512 thr = 8 waves, 128 nodes/block.
// Phase 1: 16-lane group owns one node, 8 B fp8 row-segment loads, fp32 accumulate.
// Phase 2: S (fp16, LDS) @ W via swapped-operand MFMA; W frags from global (L2-hot).
// Epilogue: inner layers write fp8 (4 B packed); last layer writes fp16 for pooling.

__global__ __launch_bounds__(512) void k_layer(
        const uchar* __restrict__ g8in,
        const int* __restrict__ rowptr, const int* __restrict__ srcs,
        const float* __restrict__ dinv,
        const _Float16* __restrict__ Wf,
        const float* __restrict__ bias,
        uchar* __restrict__ g8out, _Float16* __restrict__ g16out,
        int N, int last) {
    __shared__ _Float16 S[128 * LSTRIDE];   // 34.8 KB

    const int tid  = threadIdx.x;
    const int w    = tid >> 6;
    const int lane = tid & 63;
    const int q    = lane >> 4;       // group 0..3
    const int l16  = lane & 15;       // lane-in-group
    const int nb0  = blockIdx.x * 128;
    const int cb   = l16 * 8;         // byte (=element) offset within 128 B row

    // ---- phase 1: gather; wave w covers nodes w*16..w*16+15, group q owns q*4+it ----
    for (int it = 0; it < 4; ++it) {
        const int nl = w * 16 + q * 4 + it;
        const int node = nb0 + nl;
        float a[8];
#pragma unroll
        for (int j = 0; j < 8; j++) a[j] = 0.f;

        if (node < N) {
            acc_fp8x8(a, *(const uint2*)(g8in + (size_t)node * D + cb));  // self-loop
            const int beg = rowptr[node];
            const int end = rowptr[node + 1];
            int e = beg;
            for (; e + 3 < end; e += 4) {
                int s0 = srcs[e], s1 = srcs[e + 1], s2 = srcs[e + 2], s3 = srcs[e + 3];
                uint2 u0 = *(const uint2*)(g8in + (size_t)s0 * D + cb);
                uint2 u1 = *(const uint2*)(g8in + (size_t)s1 * D + cb);
                uint2 u2 = *(const uint2*)(g8in + (size_t)s2 * D + cb);
                uint2 u3 = *(const uint2*)(g8in + (size_t)s3 * D + cb);
                acc_fp8x8(a, u0);
                acc_fp8x8(a, u1);
                acc_fp8x8(a, u2);
                acc_fp8x8(a, u3);
            }
            for (; e < end; e++) {
                uint2 u0 = *(const uint2*)(g8in + (size_t)srcs[e] * D + cb);
                acc_fp8x8(a, u0);
            }
        }
        const float sc = (node < N) ? dinv[node] : 0.f;
        half8 o;
#pragma unroll
        for (int j = 0; j < 8; j++) o[j] = (_Float16)(a[j] * sc);
        *(half8*)(&S[nl * LSTRIDE + cb]) = o;
    }
    __syncthreads();

    // ---- phase 2: S @ W via MFMA (A_op = W frag from global/L2, B_op = S frag) ----
    f32x4 acc[8];
#pragma unroll
    for (int cc = 0; cc < 8; cc++) acc[cc] = (f32x4){0.f, 0.f, 0.f, 0.f};

    const int nl = w * 16 + l16;          // this lane's node row (B-frag)
#pragma unroll
    for (int s = 0; s < 4; s++) {
        half8 bf = *(const half8*)(&S[nl * LSTRIDE + s * 32 + q * 8]);
#pragma unroll
        for (int cc = 0; cc < 8; cc++) {
            half8 wh = *(const half8*)(Wf + (size_t)((s * 8 + cc) * 64 + lane) * 8);
            acc[cc] = __builtin_amdgcn_mfma_f32_16x16x32_f16(wh, bf, acc[cc], 0, 0, 0);
        }
    }

    // ---- epilogue: D[m = W-col = q*4+r][n = node = l16] ----
    const int node = nb0 + nl;
    if (node < N) {
        if (last) {
            _Float16* rp = g16out + (size_t)node * D + q * 4;
#pragma unroll
            for (int cc = 0; cc < 8; cc++) {
                const float4 bc = *(const float4*)(bias + cc * 16 + q * 4);
                half4v o;
                o[0] = (_Float16)fmaxf(acc[cc][0] + bc.x, 0.f);
                o[1] = (_Float16)fmaxf(acc[cc][1] + bc.y, 0.f);
                o[2] = (_Float16)fmaxf(acc[cc][2] + bc.z, 0.f);
                o[3] = (_Float16)fmaxf(acc[cc][3] + bc.w, 0.f);
                *(half4v*)(rp + cc * 16) = o;
            }
        } else {
            const float scale = dinv[node];
            uchar* rp = g8out + (size_t)node * D + q * 4;
#pragma unroll
            for (int cc = 0; cc < 8; cc++) {
                const float4 bc = *(const float4*)(bias + cc * 16 + q * 4);
                float o0 = fmaxf(acc[cc][0] + bc.x, 0.f) * scale;
                float o1 = fmaxf(acc[cc][1] + bc.y, 0.f) * scale;
                float o2 = fmaxf(acc[cc][2] + bc.z, 0.f) * scale;
                float o3 = fmaxf(acc[cc][3] + bc.w, 0.f) * scale;
                int pk = __builtin_amdgcn_cvt_pk_fp8_f32(o0, o1, 0, false);
                pk     = __builtin_amdgcn_cvt_pk_fp8_f32(o2, o3, pk, true);
                *(int*)(rp + cc * 16) = pk;   // 4 B store
            }
        }
    }
}

// ========== fused pool + MLP head: one block (256 thr) per graph ==========

__global__ __launch_bounds__(256) void k_poolhead(
        const _Float16* __restrict__ h, const int* __restrict__ batch,
        const float* __restrict__ W1, const float* __restrict__ b1,
        const float* __restrict__ W2, const float* __restrict__ b2,
        const float* __restrict__ W3, const float* __restrict__ b3,
        float* __restrict__ out, int N) {
    __shared__ int sb[2];
    __shared__ float part[4][D];
    __shared__ float v[D];
    __shared__ float z[D];
    __shared__ float red[D];

    const int g = blockIdx.x;
    const int t = threadIdx.x;

    if (t < 2) {
        int target = g + t;
        int lo = 0, hi = N;
        while (lo < hi) {
            int mid = (lo + hi) >> 1;
            if (batch[mid] < target) lo = mid + 1; else hi = mid;
        }
        sb[t] = lo;
    }
    __syncthreads();
    const int rs = sb[0], re = sb[1];

    const int w = t >> 6;
    const int lane = t & 63;
    const int c = lane * 2;

    float ax = 0.f, ay = 0.f;
    for (int r = rs + w; r < re; r += 4) {
        half2v vv = *(const half2v*)(h + (size_t)r * D + c);
        ax += (float)vv[0]; ay += (float)vv[1];
    }
    part[w][c] = ax;
    part[w][c + 1] = ay;
    __syncthreads();

    if (t < D) v[t] = part[0][t] + part[1][t] + part[2][t] + part[3][t];
    __syncthreads();

    if (t < D) {
        float s = b1[t];
        for (int k = 0; k < D; k++) s = fmaf(v[k], W1[(size_t)k * D + t], s);
        z[t] = fmaxf(s, 0.f);
    }
    __syncthreads();

    if (t < D) {
        float s = b2[t];
        for (int k = 0; k < D; k++) s = fmaf(z[k], W2[(size_t)k * D + t], s);
        red[t] = fmaxf(s, 0.f) * W3[t];
    }
    __syncthreads();
    for (int off = 64; off >= 1; off >>= 1) {
        if (t < off) red[t] += red[t + off];
        __syncthreads();
    }
    if (t == 0) out[g] = 1.f / (1.f + expf(-(red[0] + b3[0])));
}

// ================= orchestration =================

extern "C" void kernel_launch(void* const* d_in, const int* in_sizes, int n_in,
                              void* d_out, int out_size, void* d_ws, size_t ws_size,
                              hipStream_t stream) {
    const float* x     = (const float*)d_in[0];
    const int*   ei    = (const int*)d_in[1];
    const int*   batch = (const int*)d_in[2];
    const float* convW = (const float*)d_in[3];
    const float* convB = (const float*)d_in[4];
    const float* W1 = (const float*)d_in[5];
    const float* b1 = (const float*)d_in[6];
    const float* W2 = (const float*)d_in[7];
    const float* b2 = (const float*)d_in[8];
    const float* W3 = (const float*)d_in[9];
    const float* b3 = (const float*)d_in[10];
    float* out = (float*)d_out;

    const int N = in_sizes[0] / D;          // 100000
    const int E = in_sizes[1] / 2;          // 640000
    const int G = out_size;                 // 512
    const int NB = (N + 1023) / 1024;

    // ---- workspace layout ----
    char* w = (char*)d_ws;
    size_t off = 0;
    auto alloc = [&](size_t bytes) -> char* {
        char* p = w + off;
        off += (bytes + 255) & ~(size_t)255;
        return p;
    };
    float*     dinv   = (float*)alloc((size_t)N * 4);
    uchar*     g8A    = (uchar*)alloc((size_t)N * D);
    uchar*     g8B    = (uchar*)alloc((size_t)N * D);
    _Float16*  g16    = (_Float16*)alloc((size_t)N * D * 2);
    _Float16*  Wf     = (_Float16*)alloc((size_t)4 * D * D * 2);
    int*       counts = (int*)alloc((size_t)N * 4);
    int*       rowptr = (int*)alloc((size_t)(N + 1) * 4);
    int*       pidx   = (int*)alloc((size_t)E * 4);
    int*       srcs   = (int*)alloc((size_t)E * 4);
    int*       bsums  = (int*)alloc((size_t)NB * 4);

    // ---- CSR build + weight pre-pack + input convert ----
    hipMemsetAsync(counts, 0, (size_t)N * 4, stream);
    const int countBlocks = (E / 4 + 255) / 256;
    k_fat1<<<countBlocks + 32, 256, 0, stream>>>(ei, counts, pidx, E, countBlocks,
                                                 convW, Wf);
    k_scan1<<<NB, 256, 0, stream>>>(counts, rowptr, bsums, dinv, N);
    const int scanBlocks = (N + 1 + 255) / 256;
    const int cvtBlocks  = (N * (D / 8) + 255) / 256;
    k_fat2<<<scanBlocks + cvtBlocks, 256, 0, stream>>>(rowptr, bsums, NB, N, scanBlocks,
                                                       x, dinv, g8A);
    k_fill<<<(E / 4 + 255) / 256, 256, 0, stream>>>(ei, rowptr, pidx, srcs, E);

    // ---- 4 fused GCN layers (ping-pong fp8; last emits fp16) ----
    const int layer_grid = (N + 127) / 128;
    const uchar* gi = g8A;
    uchar* go = g8B;
    for (int l = 0; l < 4; l++) {
        k_layer<<<layer_grid, 512, 0, stream>>>(gi, rowptr, srcs, dinv,
                                                Wf + (size_t)l * D * D,
                                                convB + (size_t)l * D,
                                                go, g16, N, l == 3);
        const uchar* tmp = go;
        go = (uchar*)gi;
        gi = tmp;
    }

    // ---- fused pool + head ----
    k_poolhead<<<G, 256, 0, stream>>>(g16, batch, W1, b1, W2, b2, W3, b3, out, N);
}

// Round 14
// 358.537 us; speedup vs baseline: 1.0531x; 1.0531x over previous
//
#include <hip/hip_runtime.h>
#include <math.h>

#define D 128
#define LSTRIDE 136   // LDS row stride in halves

typedef _Float16 half8 __attribute__((ext_vector_type(8)));
typedef _Float16 half4v __attribute__((ext_vector_type(4)));
typedef _Float16 half2v __attribute__((ext_vector_type(2)));
typedef float f32x4 __attribute__((ext_vector_type(4)));

// ============ fat1: edge count + within-bucket rank, plus weight pre-pack ============

__global__ void k_fat1(const int* __restrict__ ei, int* __restrict__ counts,
                       int* __restrict__ pidx, int E, int countBlocks,
                       const float* __restrict__ convW, _Float16* __restrict__ Wf) {
    if ((int)blockIdx.x < countBlocks) {
        int e0 = (blockIdx.x * blockDim.x + threadIdx.x) * 4;
        if (e0 + 3 < E) {
            int4 d4 = *(const int4*)(ei + E + e0);
            int4 p;
            p.x = atomicAdd(&counts[d4.x], 1);
            p.y = atomicAdd(&counts[d4.y], 1);
            p.z = atomicAdd(&counts[d4.z], 1);
            p.w = atomicAdd(&counts[d4.w], 1);
            *(int4*)(pidx + e0) = p;
        } else {
            for (int e = e0; e < E; e++) pidx[e] = atomicAdd(&counts[ei[E + e]], 1);
        }
    } else {
        // prepw: slot = (s*8+c)*64 + lane; elem j: k = s*32+(lane>>4)*8+j, n = c*16+(lane&15)
        const int bid = blockIdx.x - countBlocks;           // 0..31
        const int l = bid >> 3;                             // layer
        const int slot = (bid & 7) * 256 + threadIdx.x;
        const float* W = convW + (size_t)l * D * D;
        const int p = slot >> 6, ln = slot & 63;
        const int s = p >> 3, c = p & 7;
        const int kbase = s * 32 + ((ln >> 4) << 3);
        const int n = (c << 4) + (ln & 15);
        half8 hv;
#pragma unroll
        for (int j = 0; j < 8; j++) hv[j] = (_Float16)W[(size_t)(kbase + j) * D + n];
        *(half8*)(Wf + (size_t)l * D * D + (size_t)slot * 8) = hv;
    }
}

// scan counts -> rowptr (exclusive, per 1024-block); emits dinv = rsqrt(count+1)
__global__ __launch_bounds__(256) void k_scan1(const int* __restrict__ counts,
                                               int* __restrict__ rowptr,
                                               int* __restrict__ bsums,
                                               float* __restrict__ dinv, int N) {
    __shared__ int sh[256];
    const int t = threadIdx.x;
    const int base = blockIdx.x * 1024 + t * 4;
    int c[4];
#pragma unroll
    for (int j = 0; j < 4; j++) c[j] = (base + j < N) ? counts[base + j] : 0;
#pragma unroll
    for (int j = 0; j < 4; j++)
        if (base + j < N) dinv[base + j] = rsqrtf((float)(c[j] + 1));
    int tsum = c[0] + c[1] + c[2] + c[3];
    sh[t] = tsum;
    __syncthreads();
    for (int off = 1; off < 256; off <<= 1) {
        int v = (t >= off) ? sh[t - off] : 0;
        __syncthreads();
        sh[t] += v;
        __syncthreads();
    }
    int run = (t == 0) ? 0 : sh[t - 1];
    if (t == 255) bsums[blockIdx.x] = sh[255];
#pragma unroll
    for (int j = 0; j < 4; j++) {
        if (base + j <= N) rowptr[base + j] = run;
        run += c[j];
    }
}

// ============ fat2: scan3 (rowptr += block prefix) + cvt (x -> fp16 g0) ============

__global__ __launch_bounds__(256) void k_fat2(int* __restrict__ rowptr,
                                              const int* __restrict__ bsums,
                                              int NB, int N, int scanBlocks,
                                              const float* __restrict__ x,
                                              const float* __restrict__ dinv,
                                              _Float16* __restrict__ g16) {
    if ((int)blockIdx.x < scanBlocks) {
        __shared__ int pre[128];
        const int t = threadIdx.x;
        if (t < 128) pre[t] = (t < NB) ? bsums[t] : 0;
        __syncthreads();
        for (int off = 1; off < 128; off <<= 1) {
            int v = (t >= off && t < 128) ? pre[t - off] : 0;
            __syncthreads();
            if (t < 128) pre[t] += v;
            __syncthreads();
        }
        int i = blockIdx.x * blockDim.x + t;
        if (i <= N) {
            int b = i >> 10;
            rowptr[i] += (b == 0) ? 0 : pre[b - 1];
        }
    } else {
        int i = (blockIdx.x - scanBlocks) * blockDim.x + threadIdx.x;
        const int n8 = N * (D / 8);
        if (i >= n8) return;
        float s = dinv[i >> 4];
        const float4 v0 = *(const float4*)(x + (size_t)i * 8);
        const float4 v1 = *(const float4*)(x + (size_t)i * 8 + 4);
        half8 h;
        h[0] = (_Float16)(v0.x * s); h[1] = (_Float16)(v0.y * s);
        h[2] = (_Float16)(v0.z * s); h[3] = (_Float16)(v0.w * s);
        h[4] = (_Float16)(v1.x * s); h[5] = (_Float16)(v1.y * s);
        h[6] = (_Float16)(v1.z * s); h[7] = (_Float16)(v1.w * s);
        *(half8*)(g16 + (size_t)i * 8) = h;
    }
}

// pass B: srcs[rowptr[dst] + pidx] = src — no atomics
__global__ void k_fill(const int* __restrict__ ei, const int* __restrict__ rowptr,
                       const int* __restrict__ pidx, int* __restrict__ srcs, int E) {
    int e0 = (blockIdx.x * blockDim.x + threadIdx.x) * 4;
    if (e0 + 3 < E) {
        int4 s4 = *(const int4*)(ei + e0);
        int4 d4 = *(const int4*)(ei + E + e0);
        int4 p4 = *(const int4*)(pidx + e0);
        int r0 = rowptr[d4.x], r1 = rowptr[d4.y], r2 = rowptr[d4.z], r3 = rowptr[d4.w];
        srcs[r0 + p4.x] = s4.x;
        srcs[r1 + p4.y] = s4.y;
        srcs[r2 + p4.z] = s4.z;
        srcs[r3 + p4.w] = s4.w;
    } else {
        for (int e = e0; e < E; e++)
            srcs[rowptr[ei[E + e]] + pidx[e]] = ei[e];
    }
}

// ============ fused layer: gout = scale ⊙ relu( (dinv ⊙ Â g) @ W + b ) ============
// R12 structure, BARRIER-FREE: wave w writes S rows [w*16, w*16+16) in phase 1 and
// reads only those rows in phase 2 — no cross-wave LDS sharing, so __syncthreads is
// replaced by a wave-local s_waitcnt lgkmcnt(0) (lockstep lanes + DS completion).
// Waves retire independently: no block-level straggler coupling.

__global__ __launch_bounds__(512) void k_layer(
        const _Float16* __restrict__ gin,
        const int* __restrict__ rowptr, const int* __restrict__ srcs,
        const float* __restrict__ dinv,
        const _Float16* __restrict__ Wf,
        const float* __restrict__ bias,
        _Float16* __restrict__ gout, int N, int last) {
    __shared__ _Float16 S[128 * LSTRIDE];   // 34.8 KB

    const int tid  = threadIdx.x;
    const int w    = tid >> 6;
    const int lane = tid & 63;
    const int q    = lane >> 4;       // group 0..3
    const int l16  = lane & 15;       // lane-in-group; col base = l16*8
    const int nb0  = blockIdx.x * 128;

    // ---- phase 1: gather; wave w covers nodes w*16..w*16+15, group q owns q*4+it ----
    const int cb = l16 * 8;
    for (int it = 0; it < 4; ++it) {
        const int nl = w * 16 + q * 4 + it;
        const int node = nb0 + nl;
        float a[8];
#pragma unroll
        for (int j = 0; j < 8; j++) a[j] = 0.f;

        if (node < N) {
            half8 sv = *(const half8*)(gin + (size_t)node * D + cb);  // self-loop
#pragma unroll
            for (int j = 0; j < 8; j++) a[j] = (float)sv[j];
            const int beg = rowptr[node];
            const int end = rowptr[node + 1];
            int e = beg;
            for (; e + 3 < end; e += 4) {
                int s0 = srcs[e], s1 = srcs[e + 1], s2 = srcs[e + 2], s3 = srcs[e + 3];
                half8 v0 = *(const half8*)(gin + (size_t)s0 * D + cb);
                half8 v1 = *(const half8*)(gin + (size_t)s1 * D + cb);
                half8 v2 = *(const half8*)(gin + (size_t)s2 * D + cb);
                half8 v3 = *(const half8*)(gin + (size_t)s3 * D + cb);
#pragma unroll
                for (int j = 0; j < 8; j++)
                    a[j] += ((float)v0[j] + (float)v1[j]) + ((float)v2[j] + (float)v3[j]);
            }
            for (; e < end; e++) {
                int s0 = srcs[e];
                half8 v0 = *(const half8*)(gin + (size_t)s0 * D + cb);
#pragma unroll
                for (int j = 0; j < 8; j++) a[j] += (float)v0[j];
            }
        }
        const float sc = (node < N) ? dinv[node] : 0.f;
        half8 o;
#pragma unroll
        for (int j = 0; j < 8; j++) o[j] = (_Float16)(a[j] * sc);
        *(half8*)(&S[nl * LSTRIDE + cb]) = o;
    }

    // wave-local LDS write->read ordering (no block barrier)
    asm volatile("s_waitcnt lgkmcnt(0)" ::: "memory");

    // ---- phase 2: S @ W via MFMA (A_op = W frag from global/L2, B_op = S frag) ----
    f32x4 acc[8];
#pragma unroll
    for (int cc = 0; cc < 8; cc++) acc[cc] = (f32x4){0.f, 0.f, 0.f, 0.f};

    const int nl = w * 16 + l16;          // this lane's node row (B-frag)
#pragma unroll
    for (int s = 0; s < 4; s++) {
        half8 bf = *(const half8*)(&S[nl * LSTRIDE + s * 32 + q * 8]);
#pragma unroll
        for (int cc = 0; cc < 8; cc++) {
            half8 wh = *(const half8*)(Wf + (size_t)((s * 8 + cc) * 64 + lane) * 8);
            acc[cc] = __builtin_amdgcn_mfma_f32_16x16x32_f16(wh, bf, acc[cc], 0, 0, 0);
        }
    }

    // epilogue: D[m = W-col = q*4+r][n = node = l16]
    const int node = nb0 + nl;
    if (node < N) {
        const float scale = last ? 1.0f : dinv[node];
        _Float16* rp = gout + (size_t)node * D + q * 4;
#pragma unroll
        for (int cc = 0; cc < 8; cc++) {
            const float4 bc = *(const float4*)(bias + cc * 16 + q * 4);
            half4v o;
            o[0] = (_Float16)(fmaxf(acc[cc][0] + bc.x, 0.f) * scale);
            o[1] = (_Float16)(fmaxf(acc[cc][1] + bc.y, 0.f) * scale);
            o[2] = (_Float16)(fmaxf(acc[cc][2] + bc.z, 0.f) * scale);
            o[3] = (_Float16)(fmaxf(acc[cc][3] + bc.w, 0.f) * scale);
            *(half4v*)(rp + cc * 16) = o;   // 8 B store
        }
    }
}

// ========== fused pool + MLP head: one block (256 thr) per graph ==========

__global__ __launch_bounds__(256) void k_poolhead(
        const _Float16* __restrict__ h, const int* __restrict__ batch,
        const float* __restrict__ W1, const float* __restrict__ b1,
        const float* __restrict__ W2, const float* __restrict__ b2,
        const float* __restrict__ W3, const float* __restrict__ b3,
        float* __restrict__ out, int N) {
    __shared__ int sb[2];
    __shared__ float part[4][D];
    __shared__ float v[D];
    __shared__ float z[D];
    __shared__ float red[D];

    const int g = blockIdx.x;
    const int t = threadIdx.x;

    if (t < 2) {
        int target = g + t;
        int lo = 0, hi = N;
        while (lo < hi) {
            int mid = (lo + hi) >> 1;
            if (batch[mid] < target) lo = mid + 1; else hi = mid;
        }
        sb[t] = lo;
    }
    __syncthreads();
    const int rs = sb[0], re = sb[1];

    const int w = t >> 6;
    const int lane = t & 63;
    const int c = lane * 2;

    float ax = 0.f, ay = 0.f;
    for (int r = rs + w; r < re; r += 4) {
        half2v vv = *(const half2v*)(h + (size_t)r * D + c);
        ax += (float)vv[0]; ay += (float)vv[1];
    }
    part[w][c] = ax;
    part[w][c + 1] = ay;
    __syncthreads();

    if (t < D) v[t] = part[0][t] + part[1][t] + part[2][t] + part[3][t];
    __syncthreads();

    if (t < D) {
        float s = b1[t];
        for (int k = 0; k < D; k++) s = fmaf(v[k], W1[(size_t)k * D + t], s);
        z[t] = fmaxf(s, 0.f);
    }
    __syncthreads();

    if (t < D) {
        float s = b2[t];
        for (int k = 0; k < D; k++) s = fmaf(z[k], W2[(size_t)k * D + t], s);
        red[t] = fmaxf(s, 0.f) * W3[t];
    }
    __syncthreads();
    for (int off = 64; off >= 1; off >>= 1) {
        if (t < off) red[t] += red[t + off];
        __syncthreads();
    }
    if (t == 0) out[g] = 1.f / (1.f + expf(-(red[0] + b3[0])));
}

// ================= orchestration =================

extern "C" void kernel_launch(void* const* d_in, const int* in_sizes, int n_in,
                              void* d_out, int out_size, void* d_ws, size_t ws_size,
                              hipStream_t stream) {
    const float* x     = (const float*)d_in[0];
    const int*   ei    = (const int*)d_in[1];
    const int*   batch = (const int*)d_in[2];
    const float* convW = (const float*)d_in[3];
    const float* convB = (const float*)d_in[4];
    const float* W1 = (const float*)d_in[5];
    const float* b1 = (const float*)d_in[6];
    const float* W2 = (const float*)d_in[7];
    const float* b2 = (const float*)d_in[8];
    const float* W3 = (const float*)d_in[9];
    const float* b3 = (const float*)d_in[10];
    float* out = (float*)d_out;

    const int N = in_sizes[0] / D;          // 100000
    const int E = in_sizes[1] / 2;          // 640000
    const int G = out_size;                 // 512
    const int NB = (N + 1023) / 1024;

    // ---- workspace layout ----
    char* w = (char*)d_ws;
    size_t off = 0;
    auto alloc = [&](size_t bytes) -> char* {
        char* p = w + off;
        off += (bytes + 255) & ~(size_t)255;
        return p;
    };
    float*     dinv   = (float*)alloc((size_t)N * 4);
    _Float16*  gA     = (_Float16*)alloc((size_t)N * D * 2);
    _Float16*  gB     = (_Float16*)alloc((size_t)N * D * 2);
    _Float16*  Wf     = (_Float16*)alloc((size_t)4 * D * D * 2);
    int*       counts = (int*)alloc((size_t)N * 4);
    int*       rowptr = (int*)alloc((size_t)(N + 1) * 4);
    int*       pidx   = (int*)alloc((size_t)E * 4);
    int*       srcs   = (int*)alloc((size_t)E * 4);
    int*       bsums  = (int*)alloc((size_t)NB * 4);

    // ---- CSR build + weight pre-pack + input convert ----
    hipMemsetAsync(counts, 0, (size_t)N * 4, stream);
    const int countBlocks = (E / 4 + 255) / 256;
    k_fat1<<<countBlocks + 32, 256, 0, stream>>>(ei, counts, pidx, E, countBlocks,
                                                 convW, Wf);
    k_scan1<<<NB, 256, 0, stream>>>(counts, rowptr, bsums, dinv, N);
    const int scanBlocks = (N + 1 + 255) / 256;
    const int cvtBlocks  = (N * (D / 8) + 255) / 256;
    k_fat2<<<scanBlocks + cvtBlocks, 256, 0, stream>>>(rowptr, bsums, NB, N, scanBlocks,
                                                       x, dinv, gA);
    k_fill<<<(E / 4 + 255) / 256, 256, 0, stream>>>(ei, rowptr, pidx, srcs, E);

    // ---- 4 fused GCN layers (ping-pong) ----
    const int layer_grid = (N + 127) / 128;
    const _Float16* gi = gA;
    _Float16* go = gB;
    for (int l = 0; l < 4; l++) {
        k_layer<<<layer_grid, 512, 0, stream>>>(gi, rowptr, srcs, dinv,
                                                Wf + (size_t)l * D * D,
                                                convB + (size_t)l * D,
                                                go, N, l == 3);
        const _Float16* tmp = go;
        go = (_Float16*)gi;
        gi = tmp;
    }

    // ---- fused pool + head ----
    k_poolhead<<<G, 256, 0, stream>>>(gi, batch, W1, b1, W2, b2, W3, b3, out, N);
}

// Round 15
// 355.353 us; speedup vs baseline: 1.0625x; 1.0090x over previous
//
#include <hip/hip_runtime.h>
#include <math.h>

#define D 128
#define LSTRIDE 136   // LDS row stride in halves

typedef _Float16 half8 __attribute__((ext_vector_type(8)));
typedef _Float16 half4v __attribute__((ext_vector_type(4)));
typedef _Float16 half2v __attribute__((ext_vector_type(2)));
typedef float f32x4 __attribute__((ext_vector_type(4)));

// ============ fat1: edge count + within-bucket rank, plus weight pre-pack ============

__global__ void k_fat1(const int* __restrict__ ei, int* __restrict__ counts,
                       int* __restrict__ pidx, int E, int countBlocks,
                       const float* __restrict__ convW, _Float16* __restrict__ Wf) {
    if ((int)blockIdx.x < countBlocks) {
        int e0 = (blockIdx.x * blockDim.x + threadIdx.x) * 4;
        if (e0 + 3 < E) {
            int4 d4 = *(const int4*)(ei + E + e0);
            int4 p;
            p.x = atomicAdd(&counts[d4.x], 1);
            p.y = atomicAdd(&counts[d4.y], 1);
            p.z = atomicAdd(&counts[d4.z], 1);
            p.w = atomicAdd(&counts[d4.w], 1);
            *(int4*)(pidx + e0) = p;
        } else {
            for (int e = e0; e < E; e++) pidx[e] = atomicAdd(&counts[ei[E + e]], 1);
        }
    } else {
        // prepw: slot = (s*8+c)*64 + lane; elem j: k = s*32+(lane>>4)*8+j, n = c*16+(lane&15)
        const int bid = blockIdx.x - countBlocks;           // 0..31
        const int l = bid >> 3;                             // layer
        const int slot = (bid & 7) * 256 + threadIdx.x;
        const float* W = convW + (size_t)l * D * D;
        const int p = slot >> 6, ln = slot & 63;
        const int s = p >> 3, c = p & 7;
        const int kbase = s * 32 + ((ln >> 4) << 3);
        const int n = (c << 4) + (ln & 15);
        half8 hv;
#pragma unroll
        for (int j = 0; j < 8; j++) hv[j] = (_Float16)W[(size_t)(kbase + j) * D + n];
        *(half8*)(Wf + (size_t)l * D * D + (size_t)slot * 8) = hv;
    }
}

// scan over PADDED counts (ceil4) -> rowptrP (16B-aligned row starts);
// emits dinv = rsqrt(count+1) and rend = start + count (pre-offset).
__global__ __launch_bounds__(256) void k_scan1(const int* __restrict__ counts,
                                               int* __restrict__ rowptrP,
                                               int* __restrict__ rend,
                                               int* __restrict__ bsums,
                                               float* __restrict__ dinv, int N) {
    __shared__ int sh[256];
    const int t = threadIdx.x;
    const int base = blockIdx.x * 1024 + t * 4;
    int c[4], pj[4];
#pragma unroll
    for (int j = 0; j < 4; j++) {
        c[j] = (base + j < N) ? counts[base + j] : 0;
        pj[j] = (c[j] + 3) & ~3;
    }
#pragma unroll
    for (int j = 0; j < 4; j++)
        if (base + j < N) dinv[base + j] = rsqrtf((float)(c[j] + 1));
    int tsum = pj[0] + pj[1] + pj[2] + pj[3];
    sh[t] = tsum;
    __syncthreads();
    for (int off = 1; off < 256; off <<= 1) {
        int v = (t >= off) ? sh[t - off] : 0;
        __syncthreads();
        sh[t] += v;
        __syncthreads();
    }
    int run = (t == 0) ? 0 : sh[t - 1];
    if (t == 255) bsums[blockIdx.x] = sh[255];
#pragma unroll
    for (int j = 0; j < 4; j++) {
        if (base + j <= N) {
            rowptrP[base + j] = run;
            if (base + j < N) rend[base + j] = run + c[j];
        }
        run += pj[j];
    }
}

// ============ fat2: scan3 (add block prefix to rowptrP & rend) + cvt ============

__global__ __launch_bounds__(256) void k_fat2(int* __restrict__ rowptrP,
                                              int* __restrict__ rend,
                                              const int* __restrict__ bsums,
                                              int NB, int N, int scanBlocks,
                                              const float* __restrict__ x,
                                              const float* __restrict__ dinv,
                                              _Float16* __restrict__ g16) {
    if ((int)blockIdx.x < scanBlocks) {
        __shared__ int pre[128];
        const int t = threadIdx.x;
        if (t < 128) pre[t] = (t < NB) ? bsums[t] : 0;
        __syncthreads();
        for (int off = 1; off < 128; off <<= 1) {
            int v = (t >= off && t < 128) ? pre[t - off] : 0;
            __syncthreads();
            if (t < 128) pre[t] += v;
            __syncthreads();
        }
        int i = blockIdx.x * blockDim.x + t;
        if (i <= N) {
            int b = i >> 10;
            int add = (b == 0) ? 0 : pre[b - 1];
            rowptrP[i] += add;
            if (i < N) rend[i] += add;
        }
    } else {
        int i = (blockIdx.x - scanBlocks) * blockDim.x + threadIdx.x;
        const int n8 = N * (D / 8);
        if (i >= n8) return;
        float s = dinv[i >> 4];
        const float4 v0 = *(const float4*)(x + (size_t)i * 8);
        const float4 v1 = *(const float4*)(x + (size_t)i * 8 + 4);
        half8 h;
        h[0] = (_Float16)(v0.x * s); h[1] = (_Float16)(v0.y * s);
        h[2] = (_Float16)(v0.z * s); h[3] = (_Float16)(v0.w * s);
        h[4] = (_Float16)(v1.x * s); h[5] = (_Float16)(v1.y * s);
        h[6] = (_Float16)(v1.z * s); h[7] = (_Float16)(v1.w * s);
        *(half8*)(g16 + (size_t)i * 8) = h;
    }
}

// pass B: srcs[rowptrP[dst] + pidx] = src — no atomics
__global__ void k_fill(const int* __restrict__ ei, const int* __restrict__ rowptrP,
                       const int* __restrict__ pidx, int* __restrict__ srcs, int E) {
    int e0 = (blockIdx.x * blockDim.x + threadIdx.x) * 4;
    if (e0 + 3 < E) {
        int4 s4 = *(const int4*)(ei + e0);
        int4 d4 = *(const int4*)(ei + E + e0);
        int4 p4 = *(const int4*)(pidx + e0);
        int r0 = rowptrP[d4.x], r1 = rowptrP[d4.y], r2 = rowptrP[d4.z], r3 = rowptrP[d4.w];
        srcs[r0 + p4.x] = s4.x;
        srcs[r1 + p4.y] = s4.y;
        srcs[r2 + p4.z] = s4.z;
        srcs[r3 + p4.w] = s4.w;
    } else {
        for (int e = e0; e < E; e++)
            srcs[rowptrP[ei[E + e]] + pidx[e]] = ei[e];
    }
}

// ============ fused layer: gout = scale ⊙ relu( (dinv ⊙ Â g) @ W + b ) ============
// R14 structure + 16B-aligned row starts: unroll-4 gather uses ONE int4 index load
// per 4 edges (srcs rows start 4-aligned). Barrier-free (wave-local LDS reuse).

__global__ __launch_bounds__(512) void k_layer(
        const _Float16* __restrict__ gin,
        const int* __restrict__ rowptrP, const int* __restrict__ rend,
        const int* __restrict__ srcs,
        const float* __restrict__ dinv,
        const _Float16* __restrict__ Wf,
        const float* __restrict__ bias,
        _Float16* __restrict__ gout, int N, int last) {
    __shared__ _Float16 S[128 * LSTRIDE];   // 34.8 KB

    const int tid  = threadIdx.x;
    const int w    = tid >> 6;
    const int lane = tid & 63;
    const int q    = lane >> 4;       // group 0..3
    const int l16  = lane & 15;       // lane-in-group; col base = l16*8
    const int nb0  = blockIdx.x * 128;

    // ---- phase 1: gather; wave w covers nodes w*16..w*16+15, group q owns q*4+it ----
    const int cb = l16 * 8;
    for (int it = 0; it < 4; ++it) {
        const int nl = w * 16 + q * 4 + it;
        const int node = nb0 + nl;
        float a[8];
#pragma unroll
        for (int j = 0; j < 8; j++) a[j] = 0.f;

        if (node < N) {
            half8 sv = *(const half8*)(gin + (size_t)node * D + cb);  // self-loop
#pragma unroll
            for (int j = 0; j < 8; j++) a[j] = (float)sv[j];
            int e = rowptrP[node];                 // 4-aligned
            const int end = rend[node];
            for (; e + 3 < end; e += 4) {
                int4 s4 = *(const int4*)(srcs + e);   // one 16 B index load
                half8 v0 = *(const half8*)(gin + (size_t)s4.x * D + cb);
                half8 v1 = *(const half8*)(gin + (size_t)s4.y * D + cb);
                half8 v2 = *(const half8*)(gin + (size_t)s4.z * D + cb);
                half8 v3 = *(const half8*)(gin + (size_t)s4.w * D + cb);
#pragma unroll
                for (int j = 0; j < 8; j++)
                    a[j] += ((float)v0[j] + (float)v1[j]) + ((float)v2[j] + (float)v3[j]);
            }
            for (; e < end; e++) {
                int s0 = srcs[e];
                half8 v0 = *(const half8*)(gin + (size_t)s0 * D + cb);
#pragma unroll
                for (int j = 0; j < 8; j++) a[j] += (float)v0[j];
            }
        }
        const float sc = (node < N) ? dinv[node] : 0.f;
        half8 o;
#pragma unroll
        for (int j = 0; j < 8; j++) o[j] = (_Float16)(a[j] * sc);
        *(half8*)(&S[nl * LSTRIDE + cb]) = o;
    }

    // wave-local LDS write->read ordering (no block barrier)
    asm volatile("s_waitcnt lgkmcnt(0)" ::: "memory");

    // ---- phase 2: S @ W via MFMA (A_op = W frag from global/L2, B_op = S frag) ----
    f32x4 acc[8];
#pragma unroll
    for (int cc = 0; cc < 8; cc++) acc[cc] = (f32x4){0.f, 0.f, 0.f, 0.f};

    const int nl = w * 16 + l16;          // this lane's node row (B-frag)
#pragma unroll
    for (int s = 0; s < 4; s++) {
        half8 bf = *(const half8*)(&S[nl * LSTRIDE + s * 32 + q * 8]);
#pragma unroll
        for (int cc = 0; cc < 8; cc++) {
            half8 wh = *(const half8*)(Wf + (size_t)((s * 8 + cc) * 64 + lane) * 8);
            acc[cc] = __builtin_amdgcn_mfma_f32_16x16x32_f16(wh, bf, acc[cc], 0, 0, 0);
        }
    }

    // epilogue: D[m = W-col = q*4+r][n = node = l16]
    const int node = nb0 + nl;
    if (node < N) {
        const float scale = last ? 1.0f : dinv[node];
        _Float16* rp = gout + (size_t)node * D + q * 4;
#pragma unroll
        for (int cc = 0; cc < 8; cc++) {
            const float4 bc = *(const float4*)(bias + cc * 16 + q * 4);
            half4v o;
            o[0] = (_Float16)(fmaxf(acc[cc][0] + bc.x, 0.f) * scale);
            o[1] = (_Float16)(fmaxf(acc[cc][1] + bc.y, 0.f) * scale);
            o[2] = (_Float16)(fmaxf(acc[cc][2] + bc.z, 0.f) * scale);
            o[3] = (_Float16)(fmaxf(acc[cc][3] + bc.w, 0.f) * scale);
            *(half4v*)(rp + cc * 16) = o;   // 8 B store
        }
    }
}

// ========== fused pool + MLP head: one block (256 thr) per graph ==========

__global__ __launch_bounds__(256) void k_poolhead(
        const _Float16* __restrict__ h, const int* __restrict__ batch,
        const float* __restrict__ W1, const float* __restrict__ b1,
        const float* __restrict__ W2, const float* __restrict__ b2,
        const float* __restrict__ W3, const float* __restrict__ b3,
        float* __restrict__ out, int N) {
    __shared__ int sb[2];
    __shared__ float part[4][D];
    __shared__ float v[D];
    __shared__ float z[D];
    __shared__ float red[D];

    const int g = blockIdx.x;
    const int t = threadIdx.x;

    if (t < 2) {
        int target = g + t;
        int lo = 0, hi = N;
        while (lo < hi) {
            int mid = (lo + hi) >> 1;
            if (batch[mid] < target) lo = mid + 1; else hi = mid;
        }
        sb[t] = lo;
    }
    __syncthreads();
    const int rs = sb[0], re = sb[1];

    const int w = t >> 6;
    const int lane = t & 63;
    const int c = lane * 2;

    float ax = 0.f, ay = 0.f;
    for (int r = rs + w; r < re; r += 4) {
        half2v vv = *(const half2v*)(h + (size_t)r * D + c);
        ax += (float)vv[0]; ay += (float)vv[1];
    }
    part[w][c] = ax;
    part[w][c + 1] = ay;
    __syncthreads();

    if (t < D) v[t] = part[0][t] + part[1][t] + part[2][t] + part[3][t];
    __syncthreads();

    if (t < D) {
        float s = b1[t];
        for (int k = 0; k < D; k++) s = fmaf(v[k], W1[(size_t)k * D + t], s);
        z[t] = fmaxf(s, 0.f);
    }
    __syncthreads();

    if (t < D) {
        float s = b2[t];
        for (int k = 0; k < D; k++) s = fmaf(z[k], W2[(size_t)k * D + t], s);
        red[t] = fmaxf(s, 0.f) * W3[t];
    }
    __syncthreads();
    for (int off = 64; off >= 1; off >>= 1) {
        if (t < off) red[t] += red[t + off];
        __syncthreads();
    }
    if (t == 0) out[g] = 1.f / (1.f + expf(-(red[0] + b3[0])));
}

// ================= orchestration =================

extern "C" void kernel_launch(void* const* d_in, const int* in_sizes, int n_in,
                              void* d_out, int out_size, void* d_ws, size_t ws_size,
                              hipStream_t stream) {
    const float* x     = (const float*)d_in[0];
    const int*   ei    = (const int*)d_in[1];
    const int*   batch = (const int*)d_in[2];
    const float* convW = (const float*)d_in[3];
    const float* convB = (const float*)d_in[4];
    const float* W1 = (const float*)d_in[5];
    const float* b1 = (const float*)d_in[6];
    const float* W2 = (const float*)d_in[7];
    const float* b2 = (const float*)d_in[8];
    const float* W3 = (const float*)d_in[9];
    const float* b3 = (const float*)d_in[10];
    float* out = (float*)d_out;

    const int N = in_sizes[0] / D;          // 100000
    const int E = in_sizes[1] / 2;          // 640000
    const int G = out_size;                 // 512
    const int NB = (N + 1023) / 1024;

    // ---- workspace layout ----
    char* w = (char*)d_ws;
    size_t off = 0;
    auto alloc = [&](size_t bytes) -> char* {
        char* p = w + off;
        off += (bytes + 255) & ~(size_t)255;
        return p;
    };
    float*     dinv   = (float*)alloc((size_t)N * 4);
    _Float16*  gA     = (_Float16*)alloc((size_t)N * D * 2);
    _Float16*  gB     = (_Float16*)alloc((size_t)N * D * 2);
    _Float16*  Wf     = (_Float16*)alloc((size_t)4 * D * D * 2);
    int*       counts = (int*)alloc((size_t)N * 4);
    int*       rowptrP= (int*)alloc((size_t)(N + 1) * 4);
    int*       rend   = (int*)alloc((size_t)N * 4);
    int*       pidx   = (int*)alloc((size_t)E * 4);
    int*       srcs   = (int*)alloc((size_t)(E + 3 * N) * 4);
    int*       bsums  = (int*)alloc((size_t)NB * 4);

    // ---- CSR build + weight pre-pack + input convert ----
    hipMemsetAsync(counts, 0, (size_t)N * 4, stream);
    const int countBlocks = (E / 4 + 255) / 256;
    k_fat1<<<countBlocks + 32, 256, 0, stream>>>(ei, counts, pidx, E, countBlocks,
                                                 convW, Wf);
    k_scan1<<<NB, 256, 0, stream>>>(counts, rowptrP, rend, bsums, dinv, N);
    const int scanBlocks = (N + 1 + 255) / 256;
    const int cvtBlocks  = (N * (D / 8) + 255) / 256;
    k_fat2<<<scanBlocks + cvtBlocks, 256, 0, stream>>>(rowptrP, rend, bsums, NB, N,
                                                       scanBlocks, x, dinv, gA);
    k_fill<<<(E / 4 + 255) / 256, 256, 0, stream>>>(ei, rowptrP, pidx, srcs, E);

    // ---- 4 fused GCN layers (ping-pong) ----
    const int layer_grid = (N + 127) / 128;
    const _Float16* gi = gA;
    _Float16* go = gB;
    for (int l = 0; l < 4; l++) {
        k_layer<<<layer_grid, 512, 0, stream>>>(gi, rowptrP, rend, srcs, dinv,
                                                Wf + (size_t)l * D * D,
                                                convB + (size_t)l * D,
                                                go, N, l == 3);
        const _Float16* tmp = go;
        go = (_Float16*)gi;
        gi = tmp;
    }

    // ---- fused pool + head ----
    k_poolhead<<<G, 256, 0, stream>>>(gi, batch, W1, b1, W2, b2, W3, b3, out, N);
}